// Round 6
// baseline (227.195 us; speedup 1.0000x reference)
//
#include <hip/hip_runtime.h>
#include <math.h>

#define NPTS 500000
#define TSIZE 524288u
#define TMASK (TSIZE - 1u)
#define CHUNKS 1954        // ceil(NPTS/256)
#define SLICE 245          // ceil(CHUNKS/8): pool-level chunks per XCD
#define NBKT 32768         // 15-bit Morton buckets (32^3)

struct ResArgs { float r[16]; };

// ---- core per-(point,level) math: 6-request gather + trilinear blend -----
__device__ __forceinline__ float2 mhe_core(
    float x0, float x1, float x2,
    const float* __restrict__ tbl, int l, float res)
{
    float s0 = x0 * res, s1 = x1 * res, s2 = x2 * res;
    float f0 = floorf(s0), f1 = floorf(s1), f2 = floorf(s2);
    float w0 = s0 - f0, w1 = s1 - f1, w2 = s2 - f2;
    unsigned u0 = (unsigned)f0, u1 = (unsigned)f1, u2 = (unsigned)f2;

    unsigned b0 = u1 * 2654435761u, b1 = (u1 + 1u) * 2654435761u;
    unsigned c0 = u2 * 805459861u,  c1 = (u2 + 1u) * 805459861u;

    const float2* t  = (const float2*)tbl + (size_t)l * TSIZE;
    const float4* t4 = (const float4*)t;

    float v0a = 1.f - w0, v0b = w0;
    float v1a = 1.f - w1, v1b = w1;
    float v2a = 1.f - w2, v2b = w2;

    bool odd = (u0 & 1u) != 0u;
    unsigned u0p1 = u0 + 1u;

    float o0 = 0.f, o1 = 0.f;
#pragma unroll
    for (int j = 0; j < 4; ++j) {               // j bits: (j&1)=dy, (j&2)=dz
        unsigned bc = ((j & 1) ? b1 : b0) ^ ((j & 2) ? c1 : c0);
        unsigned e0 = (u0 ^ bc) & TMASK;
        float4 q = t4[e0 >> 1];                 // entries {e0&~1, e0|1}
        float2 lo = make_float2(q.x, q.y);
        float2 hi = make_float2(q.z, q.w);
        float2 fc0 = (e0 & 1u) ? hi : lo;
        float2 fc1 = (e0 & 1u) ? lo : hi;       // valid iff u0 even
        if (odd) {                              // predicated odd-lane fixup
            unsigned e1 = (u0p1 ^ bc) & TMASK;
            fc1 = t[e1];
        }
        float wyz = ((j & 1) ? v1b : v1a) * ((j & 2) ? v2b : v2a);
        o0 = fmaf(v0a * wyz, fc0.x, o0);
        o1 = fmaf(v0a * wyz, fc0.y, o1);
        o0 = fmaf(v0b * wyz, fc1.x, o0);
        o1 = fmaf(v0b * wyz, fc1.y, o1);
    }
    return make_float2(o0, o1);
}

// ---- Morton bucket (5 bits/dim interleaved, 32^3 = 32768 buckets) --------
__device__ __forceinline__ unsigned mspread5(unsigned v) {
    return (v & 1u) | ((v & 2u) << 2) | ((v & 4u) << 4)
         | ((v & 8u) << 6) | ((v & 16u) << 8);
}
__device__ __forceinline__ unsigned bucket_of(float x0, float x1, float x2) {
    unsigned bx = (unsigned)min(31, (int)(x0 * 32.f));
    unsigned by = (unsigned)min(31, (int)(x1 * 32.f));
    unsigned bz = (unsigned)min(31, (int)(x2 * 32.f));
    return mspread5(bx) | (mspread5(by) << 1) | (mspread5(bz) << 2);
}

// ---- sort pipeline: histogram -> scan -> scatter -------------------------
__global__ __launch_bounds__(256) void sort_count(
    const float* __restrict__ x, int* __restrict__ hist)
{
    int p = blockIdx.x * 256 + threadIdx.x;
    if (p >= NPTS) return;
    unsigned b = bucket_of(x[p * 3], x[p * 3 + 1], x[p * 3 + 2]);
    atomicAdd(&hist[b], 1);
}

__global__ __launch_bounds__(1024) void sort_scan(
    const int* __restrict__ hist, int* __restrict__ ofs)
{
    __shared__ int sums[1024];
    int t = threadIdx.x;
    int base = t * 32;
    int loc[32];
    int s = 0;
#pragma unroll
    for (int i = 0; i < 32; ++i) { loc[i] = hist[base + i]; s += loc[i]; }
    sums[t] = s;
    __syncthreads();
    // Hillis-Steele inclusive scan over 1024 per-thread sums
    for (int off = 1; off < 1024; off <<= 1) {
        int v = (t >= off) ? sums[t - off] : 0;
        __syncthreads();
        sums[t] += v;
        __syncthreads();
    }
    int run = sums[t] - s;          // exclusive prefix of this thread's chunk
#pragma unroll
    for (int i = 0; i < 32; ++i) { ofs[base + i] = run; run += loc[i]; }
}

__global__ __launch_bounds__(256) void sort_scatter(
    const float* __restrict__ x, int* __restrict__ ofs,
    float4* __restrict__ sx, int* __restrict__ perm)
{
    int p = blockIdx.x * 256 + threadIdx.x;
    if (p >= NPTS) return;
    float x0 = x[p * 3], x1 = x[p * 3 + 1], x2 = x[p * 3 + 2];
    unsigned b = bucket_of(x0, x1, x2);
    int pos = atomicAdd(&ofs[b], 1);
    sx[pos] = make_float4(x0, x1, x2, 0.f);
    perm[pos] = p;
}

// ---- gather: anchors (8..15, one per XCD) + pool (0..7, split 8 ways) ----
// SORTED: reads Morton-ordered float4 points; co-cell points adjacent ->
// coarse-level table lines become L1 hits instead of L2 requests.
template <bool SORTED>
__global__ __launch_bounds__(256) void mhe_gather(
    const float* __restrict__ x, const float4* __restrict__ sx,
    const float* __restrict__ tbl, float2* __restrict__ ws, ResArgs ra)
{
    int b = blockIdx.x;
    int xcd = b & 7;
    int t = b >> 3;
    int l, chunk;
    if (t < CHUNKS) {               // Phase A: anchored fine level
        l = 8 + xcd;
        chunk = t;
    } else {                        // Phase B: pooled levels 0..7, level-major
        int u = t - CHUNKS;
        int pl = u / SLICE;
        int sc = u - pl * SLICE;
        l = pl;
        chunk = xcd * SLICE + sc;
        if (chunk >= CHUNKS) return;
    }
    int p = chunk * 256 + threadIdx.x;
    if (p >= NPTS) return;

    float x0, x1, x2;
    if (SORTED) { float4 v = sx[p]; x0 = v.x; x1 = v.y; x2 = v.z; }
    else        { x0 = x[p * 3]; x1 = x[p * 3 + 1]; x2 = x[p * 3 + 2]; }

    float2 o = mhe_core(x0, x1, x2, tbl, l, ra.r[l]);
    ws[(size_t)l * NPTS + p] = o;   // coalesced (p = sorted position)
}

// ---- transpose + un-permute: ws[l][sp] -> out[perm[sp]][l] ---------------
// Each output point is one FULL 128B line (16 x float2), so scattered
// per-point line writes cost the same 8 line-requests/wave as coalesced.
template <bool PERM>
__global__ __launch_bounds__(256) void mhe_transpose(
    const float2* __restrict__ ws, const int* __restrict__ perm,
    float2* __restrict__ out)
{
    __shared__ float2 tile[16][65];
    __shared__ int pidx[64];
    int p0 = blockIdx.x * 64;
    int t = threadIdx.x;

    int pc = t & 63;
#pragma unroll
    for (int i = 0; i < 4; ++i) {
        int l = (t >> 6) + i * 4;
        int p = p0 + pc;
        if (p < NPTS) tile[l][pc] = ws[(size_t)l * NPTS + p];
    }
    if (PERM && t < 64) {
        int p = p0 + t;
        pidx[t] = (p < NPTS) ? perm[p] : 0;
    }
    __syncthreads();

    float4* out4 = (float4*)out;
#pragma unroll
    for (int i = 0; i < 2; ++i) {
        int idx = t + i * 256;      // 512 float4 per block
        int pt = idx >> 3, q = idx & 7;
        int p = p0 + pt;
        if (p >= NPTS) continue;
        int dp = PERM ? pidx[pt] : p;
        float2 a = tile[2 * q][pt];
        float2 b2 = tile[2 * q + 1][pt];
        out4[(size_t)dp * 8 + q] = make_float4(a.x, a.y, b2.x, b2.y);
    }
}

// ---- Fallback: direct-out single kernel (tiny ws) ------------------------
__global__ __launch_bounds__(256) void mhe_direct(
    const float* __restrict__ x, const float* __restrict__ tbl,
    float* __restrict__ out, ResArgs ra)
{
    int gid = blockIdx.x * 256 + threadIdx.x;
    int p = gid >> 4;
    int l = gid & 15;
    if (p >= NPTS) return;
    float2 o = mhe_core(x[p * 3], x[p * 3 + 1], x[p * 3 + 2], tbl, l, ra.r[l]);
    ((float2*)out)[(size_t)p * 16 + l] = o;
}

extern "C" void kernel_launch(void* const* d_in, const int* in_sizes, int n_in,
                              void* d_out, int out_size, void* d_ws, size_t ws_size,
                              hipStream_t stream) {
    const float* x   = (const float*)d_in[0];
    const float* tbl = (const float*)d_in[1];
    float* out = (float*)d_out;

    // RES computed on HOST with libm doubles (bit-exact vs numpy): levels
    // 3,6,9,12,15 land exactly on 32/64/128/256/512; device ulp flips floor().
    ResArgs ra;
    double bb = exp((log(512.0) - log(16.0)) / 15.0);
    for (int l = 0; l < 16; ++l)
        ra.r[l] = (float)floor(16.0 * pow(bb, (double)l));

    // ws carve-up (bytes)
    const size_t WS_LV   = 0;                       // float2[16][NPTS] = 64 MB
    const size_t WS_SX   = 64000000;                // float4[NPTS]    =  8 MB
    const size_t WS_PERM = 72000000;                // int[NPTS]       =  2 MB
    const size_t WS_HIST = 74000000;                // int[NBKT]
    const size_t WS_OFS  = 74131072;                // int[NBKT]
    const size_t WS_NEW  = 74262144;
    const size_t WS_T2   = (size_t)NPTS * 16 * sizeof(float2);  // 64 MB

    int gather_grid = 8 * (CHUNKS + 8 * SLICE);     // 31312
    int tp_grid = (NPTS + 63) / 64;                 // 7813

    if (ws_size >= WS_NEW) {
        char* w = (char*)d_ws;
        float2* ws_lv = (float2*)(w + WS_LV);
        float4* sx    = (float4*)(w + WS_SX);
        int* perm     = (int*)(w + WS_PERM);
        int* hist     = (int*)(w + WS_HIST);
        int* ofs      = (int*)(w + WS_OFS);

        hipMemsetAsync(hist, 0, NBKT * sizeof(int), stream);
        sort_count<<<CHUNKS, 256, 0, stream>>>(x, hist);
        sort_scan<<<1, 1024, 0, stream>>>(hist, ofs);
        sort_scatter<<<CHUNKS, 256, 0, stream>>>(x, ofs, sx, perm);

        mhe_gather<true><<<gather_grid, 256, 0, stream>>>(x, sx, tbl, ws_lv, ra);
        mhe_transpose<true><<<tp_grid, 256, 0, stream>>>(ws_lv, perm,
                                                         (float2*)out);
    } else if (ws_size >= WS_T2) {
        float2* ws_lv = (float2*)d_ws;
        mhe_gather<false><<<gather_grid, 256, 0, stream>>>(x, nullptr, tbl,
                                                           ws_lv, ra);
        mhe_transpose<false><<<tp_grid, 256, 0, stream>>>(ws_lv, nullptr,
                                                          (float2*)out);
    } else {
        mhe_direct<<<(NPTS * 16 + 255) / 256, 256, 0, stream>>>(x, tbl, out, ra);
    }
}

// Round 7
// 222.702 us; speedup vs baseline: 1.0202x; 1.0202x over previous
//
#include <hip/hip_runtime.h>
#include <math.h>

#define NPTS 500000
#define TSIZE 524288u
#define TMASK (TSIZE - 1u)
#define CHUNKS 1954        // ceil(NPTS/256)
#define SLICE 245          // ceil(CHUNKS/8): pool-level chunks per XCD
#define NBKT 32768         // 15-bit Morton buckets (32^3)
#define NBLK 128           // NBKT / 256

struct ResArgs { float r[16]; };

// ---- core per-(point,level) math: 6-request gather + trilinear blend -----
__device__ __forceinline__ float2 mhe_core(
    float x0, float x1, float x2,
    const float* __restrict__ tbl, int l, float res)
{
    float s0 = x0 * res, s1 = x1 * res, s2 = x2 * res;
    float f0 = floorf(s0), f1 = floorf(s1), f2 = floorf(s2);
    float w0 = s0 - f0, w1 = s1 - f1, w2 = s2 - f2;
    unsigned u0 = (unsigned)f0, u1 = (unsigned)f1, u2 = (unsigned)f2;

    unsigned b0 = u1 * 2654435761u, b1 = (u1 + 1u) * 2654435761u;
    unsigned c0 = u2 * 805459861u,  c1 = (u2 + 1u) * 805459861u;

    const float2* t  = (const float2*)tbl + (size_t)l * TSIZE;
    const float4* t4 = (const float4*)t;

    float v0a = 1.f - w0, v0b = w0;
    float v1a = 1.f - w1, v1b = w1;
    float v2a = 1.f - w2, v2b = w2;

    bool odd = (u0 & 1u) != 0u;
    unsigned u0p1 = u0 + 1u;

    float o0 = 0.f, o1 = 0.f;
#pragma unroll
    for (int j = 0; j < 4; ++j) {               // j bits: (j&1)=dy, (j&2)=dz
        unsigned bc = ((j & 1) ? b1 : b0) ^ ((j & 2) ? c1 : c0);
        unsigned e0 = (u0 ^ bc) & TMASK;
        float4 q = t4[e0 >> 1];                 // entries {e0&~1, e0|1}
        float2 lo = make_float2(q.x, q.y);
        float2 hi = make_float2(q.z, q.w);
        float2 fc0 = (e0 & 1u) ? hi : lo;
        float2 fc1 = (e0 & 1u) ? lo : hi;       // valid iff u0 even
        if (odd) {                              // predicated odd-lane fixup
            unsigned e1 = (u0p1 ^ bc) & TMASK;
            fc1 = t[e1];
        }
        float wyz = ((j & 1) ? v1b : v1a) * ((j & 2) ? v2b : v2a);
        o0 = fmaf(v0a * wyz, fc0.x, o0);
        o1 = fmaf(v0a * wyz, fc0.y, o1);
        o0 = fmaf(v0b * wyz, fc1.x, o0);
        o1 = fmaf(v0b * wyz, fc1.y, o1);
    }
    return make_float2(o0, o1);
}

// ---- Morton bucket (5 bits/dim interleaved, 32^3 = 32768 buckets) --------
__device__ __forceinline__ unsigned mspread5(unsigned v) {
    return (v & 1u) | ((v & 2u) << 2) | ((v & 4u) << 4)
         | ((v & 8u) << 6) | ((v & 16u) << 8);
}
__device__ __forceinline__ unsigned bucket_of(float x0, float x1, float x2) {
    unsigned bx = (unsigned)min(31, (int)(x0 * 32.f));
    unsigned by = (unsigned)min(31, (int)(x1 * 32.f));
    unsigned bz = (unsigned)min(31, (int)(x2 * 32.f));
    return mspread5(bx) | (mspread5(by) << 1) | (mspread5(bz) << 2);
}

// ---- sort pipeline: histogram -> 3-stage hierarchical scan -> scatter ----
__global__ __launch_bounds__(256) void sort_count(
    const float* __restrict__ x, int* __restrict__ hist)
{
    int p = blockIdx.x * 256 + threadIdx.x;
    if (p >= NPTS) return;
    unsigned b = bucket_of(x[p * 3], x[p * 3 + 1], x[p * 3 + 2]);
    atomicAdd(&hist[b], 1);
}

// K1: per-256-bucket block sums (NBLK blocks)
__global__ __launch_bounds__(256) void scan_partial(
    const int* __restrict__ hist, int* __restrict__ bsum)
{
    __shared__ int s[256];
    int t = threadIdx.x;
    s[t] = hist[blockIdx.x * 256 + t];
    __syncthreads();
    for (int o = 128; o > 0; o >>= 1) {
        if (t < o) s[t] += s[t + o];
        __syncthreads();
    }
    if (t == 0) bsum[blockIdx.x] = s[0];
}

// K2: exclusive scan of the NBLK block sums (1 block)
__global__ __launch_bounds__(NBLK) void scan_top(
    const int* __restrict__ bsum, int* __restrict__ bpre)
{
    __shared__ int s[NBLK];
    int t = threadIdx.x;
    int v = bsum[t];
    s[t] = v;
    __syncthreads();
    for (int o = 1; o < NBLK; o <<= 1) {
        int u = (t >= o) ? s[t - o] : 0;
        __syncthreads();
        s[t] += u;
        __syncthreads();
    }
    bpre[t] = s[t] - v;   // exclusive prefix
}

// K3: local exclusive scan within each 256-bucket block + add block prefix
__global__ __launch_bounds__(256) void scan_final(
    const int* __restrict__ hist, const int* __restrict__ bpre,
    int* __restrict__ ofs)
{
    __shared__ int s[256];
    int t = threadIdx.x;
    int v = hist[blockIdx.x * 256 + t];
    s[t] = v;
    __syncthreads();
    for (int o = 1; o < 256; o <<= 1) {
        int u = (t >= o) ? s[t - o] : 0;
        __syncthreads();
        s[t] += u;
        __syncthreads();
    }
    ofs[blockIdx.x * 256 + t] = bpre[blockIdx.x] + s[t] - v;
}

__global__ __launch_bounds__(256) void sort_scatter(
    const float* __restrict__ x, int* __restrict__ ofs,
    float4* __restrict__ sx, int* __restrict__ perm)
{
    int p = blockIdx.x * 256 + threadIdx.x;
    if (p >= NPTS) return;
    float x0 = x[p * 3], x1 = x[p * 3 + 1], x2 = x[p * 3 + 2];
    unsigned b = bucket_of(x0, x1, x2);
    int pos = atomicAdd(&ofs[b], 1);
    sx[pos] = make_float4(x0, x1, x2, 0.f);
    perm[pos] = p;
}

// ---- gather: anchors (8..15, one per XCD) + pool (0..7, split 8 ways) ----
template <bool SORTED>
__global__ __launch_bounds__(256) void mhe_gather(
    const float* __restrict__ x, const float4* __restrict__ sx,
    const float* __restrict__ tbl, float2* __restrict__ ws, ResArgs ra)
{
    int b = blockIdx.x;
    int xcd = b & 7;
    int t = b >> 3;
    int l, chunk;
    if (t < CHUNKS) {               // Phase A: anchored fine level
        l = 8 + xcd;
        chunk = t;
    } else {                        // Phase B: pooled levels 0..7, level-major
        int u = t - CHUNKS;
        int pl = u / SLICE;
        int sc = u - pl * SLICE;
        l = pl;
        chunk = xcd * SLICE + sc;
        if (chunk >= CHUNKS) return;
    }
    int p = chunk * 256 + threadIdx.x;
    if (p >= NPTS) return;

    float x0, x1, x2;
    if (SORTED) { float4 v = sx[p]; x0 = v.x; x1 = v.y; x2 = v.z; }
    else        { x0 = x[p * 3]; x1 = x[p * 3 + 1]; x2 = x[p * 3 + 2]; }

    float2 o = mhe_core(x0, x1, x2, tbl, l, ra.r[l]);
    ws[(size_t)l * NPTS + p] = o;   // coalesced (p = sorted position)
}

// ---- transpose + un-permute: ws[l][sp] -> out[perm[sp]][l] ---------------
template <bool PERM>
__global__ __launch_bounds__(256) void mhe_transpose(
    const float2* __restrict__ ws, const int* __restrict__ perm,
    float2* __restrict__ out)
{
    __shared__ float2 tile[16][65];
    __shared__ int pidx[64];
    int p0 = blockIdx.x * 64;
    int t = threadIdx.x;

    int pc = t & 63;
#pragma unroll
    for (int i = 0; i < 4; ++i) {
        int l = (t >> 6) + i * 4;
        int p = p0 + pc;
        if (p < NPTS) tile[l][pc] = ws[(size_t)l * NPTS + p];
    }
    if (PERM && t < 64) {
        int p = p0 + t;
        pidx[t] = (p < NPTS) ? perm[p] : 0;
    }
    __syncthreads();

    float4* out4 = (float4*)out;
#pragma unroll
    for (int i = 0; i < 2; ++i) {
        int idx = t + i * 256;      // 512 float4 per block
        int pt = idx >> 3, q = idx & 7;
        int p = p0 + pt;
        if (p >= NPTS) continue;
        int dp = PERM ? pidx[pt] : p;
        float2 a = tile[2 * q][pt];
        float2 b2 = tile[2 * q + 1][pt];
        out4[(size_t)dp * 8 + q] = make_float4(a.x, a.y, b2.x, b2.y);
    }
}

// ---- Fallback: direct-out single kernel (tiny ws) ------------------------
__global__ __launch_bounds__(256) void mhe_direct(
    const float* __restrict__ x, const float* __restrict__ tbl,
    float* __restrict__ out, ResArgs ra)
{
    int gid = blockIdx.x * 256 + threadIdx.x;
    int p = gid >> 4;
    int l = gid & 15;
    if (p >= NPTS) return;
    float2 o = mhe_core(x[p * 3], x[p * 3 + 1], x[p * 3 + 2], tbl, l, ra.r[l]);
    ((float2*)out)[(size_t)p * 16 + l] = o;
}

extern "C" void kernel_launch(void* const* d_in, const int* in_sizes, int n_in,
                              void* d_out, int out_size, void* d_ws, size_t ws_size,
                              hipStream_t stream) {
    const float* x   = (const float*)d_in[0];
    const float* tbl = (const float*)d_in[1];
    float* out = (float*)d_out;

    // RES computed on HOST with libm doubles (bit-exact vs numpy): levels
    // 3,6,9,12,15 land exactly on 32/64/128/256/512; device ulp flips floor().
    ResArgs ra;
    double bb = exp((log(512.0) - log(16.0)) / 15.0);
    for (int l = 0; l < 16; ++l)
        ra.r[l] = (float)floor(16.0 * pow(bb, (double)l));

    // ws carve-up (bytes)
    const size_t WS_LV   = 0;                       // float2[16][NPTS] = 64 MB
    const size_t WS_SX   = 64000000;                // float4[NPTS]    =  8 MB
    const size_t WS_PERM = 72000000;                // int[NPTS]       =  2 MB
    const size_t WS_HIST = 74000000;                // int[NBKT]
    const size_t WS_OFS  = 74131072;                // int[NBKT]
    const size_t WS_BSUM = 74262144;                // int[NBLK]
    const size_t WS_BPRE = 74263168;                // int[NBLK]
    const size_t WS_NEW  = 74264192;
    const size_t WS_T2   = (size_t)NPTS * 16 * sizeof(float2);  // 64 MB

    int gather_grid = 8 * (CHUNKS + 8 * SLICE);     // 31312
    int tp_grid = (NPTS + 63) / 64;                 // 7813

    if (ws_size >= WS_NEW) {
        char* w = (char*)d_ws;
        float2* ws_lv = (float2*)(w + WS_LV);
        float4* sx    = (float4*)(w + WS_SX);
        int* perm     = (int*)(w + WS_PERM);
        int* hist     = (int*)(w + WS_HIST);
        int* ofs      = (int*)(w + WS_OFS);
        int* bsum     = (int*)(w + WS_BSUM);
        int* bpre     = (int*)(w + WS_BPRE);

        hipMemsetAsync(hist, 0, NBKT * sizeof(int), stream);
        sort_count<<<CHUNKS, 256, 0, stream>>>(x, hist);
        scan_partial<<<NBLK, 256, 0, stream>>>(hist, bsum);
        scan_top<<<1, NBLK, 0, stream>>>(bsum, bpre);
        scan_final<<<NBLK, 256, 0, stream>>>(hist, bpre, ofs);
        sort_scatter<<<CHUNKS, 256, 0, stream>>>(x, ofs, sx, perm);

        mhe_gather<true><<<gather_grid, 256, 0, stream>>>(x, sx, tbl, ws_lv, ra);
        mhe_transpose<true><<<tp_grid, 256, 0, stream>>>(ws_lv, perm,
                                                         (float2*)out);
    } else if (ws_size >= WS_T2) {
        float2* ws_lv = (float2*)d_ws;
        mhe_gather<false><<<gather_grid, 256, 0, stream>>>(x, nullptr, tbl,
                                                           ws_lv, ra);
        mhe_transpose<false><<<tp_grid, 256, 0, stream>>>(ws_lv, nullptr,
                                                          (float2*)out);
    } else {
        mhe_direct<<<(NPTS * 16 + 255) / 256, 256, 0, stream>>>(x, tbl, out, ra);
    }
}

// Round 8
// 221.795 us; speedup vs baseline: 1.0243x; 1.0041x over previous
//
#include <hip/hip_runtime.h>
#include <math.h>

#define NPTS 500000
#define TSIZE 524288u
#define TMASK (TSIZE - 1u)
#define CHUNKS 1954        // ceil(NPTS/256) = anchor tasks per XCD
#define SLICE 245          // ceil(CHUNKS/8): pool-level chunks per XCD
#define POOL_A (6 * SLICE) // 1470: interleaved pool units (levels 0..5)
#define POOL_B (2 * SLICE) // 490:  trailing pool units (levels 6,7)
#define TASKS (CHUNKS + POOL_A + POOL_B)   // 3914 per XCD
#define NBKT 32768         // 15-bit Morton buckets (32^3)
#define NBLK 128           // NBKT / 256

struct ResArgs { float r[16]; };

// ---- core per-(point,level) math: 6-request gather + trilinear blend -----
__device__ __forceinline__ float2 mhe_core(
    float x0, float x1, float x2,
    const float* __restrict__ tbl, int l, float res)
{
    float s0 = x0 * res, s1 = x1 * res, s2 = x2 * res;
    float f0 = floorf(s0), f1 = floorf(s1), f2 = floorf(s2);
    float w0 = s0 - f0, w1 = s1 - f1, w2 = s2 - f2;
    unsigned u0 = (unsigned)f0, u1 = (unsigned)f1, u2 = (unsigned)f2;

    unsigned b0 = u1 * 2654435761u, b1 = (u1 + 1u) * 2654435761u;
    unsigned c0 = u2 * 805459861u,  c1 = (u2 + 1u) * 805459861u;

    const float2* t  = (const float2*)tbl + (size_t)l * TSIZE;
    const float4* t4 = (const float4*)t;

    float v0a = 1.f - w0, v0b = w0;
    float v1a = 1.f - w1, v1b = w1;
    float v2a = 1.f - w2, v2b = w2;

    bool odd = (u0 & 1u) != 0u;
    unsigned u0p1 = u0 + 1u;

    float o0 = 0.f, o1 = 0.f;
#pragma unroll
    for (int j = 0; j < 4; ++j) {               // j bits: (j&1)=dy, (j&2)=dz
        unsigned bc = ((j & 1) ? b1 : b0) ^ ((j & 2) ? c1 : c0);
        unsigned e0 = (u0 ^ bc) & TMASK;
        float4 q = t4[e0 >> 1];                 // entries {e0&~1, e0|1}
        float2 lo = make_float2(q.x, q.y);
        float2 hi = make_float2(q.z, q.w);
        float2 fc0 = (e0 & 1u) ? hi : lo;
        float2 fc1 = (e0 & 1u) ? lo : hi;       // valid iff u0 even
        if (odd) {                              // predicated odd-lane fixup
            unsigned e1 = (u0p1 ^ bc) & TMASK;
            fc1 = t[e1];
        }
        float wyz = ((j & 1) ? v1b : v1a) * ((j & 2) ? v2b : v2a);
        o0 = fmaf(v0a * wyz, fc0.x, o0);
        o1 = fmaf(v0a * wyz, fc0.y, o1);
        o0 = fmaf(v0b * wyz, fc1.x, o0);
        o1 = fmaf(v0b * wyz, fc1.y, o1);
    }
    return make_float2(o0, o1);
}

// ---- Morton bucket (5 bits/dim interleaved, 32^3 = 32768 buckets) --------
__device__ __forceinline__ unsigned mspread5(unsigned v) {
    return (v & 1u) | ((v & 2u) << 2) | ((v & 4u) << 4)
         | ((v & 8u) << 6) | ((v & 16u) << 8);
}
__device__ __forceinline__ unsigned bucket_of(float x0, float x1, float x2) {
    unsigned bx = (unsigned)min(31, (int)(x0 * 32.f));
    unsigned by = (unsigned)min(31, (int)(x1 * 32.f));
    unsigned bz = (unsigned)min(31, (int)(x2 * 32.f));
    return mspread5(bx) | (mspread5(by) << 1) | (mspread5(bz) << 2);
}

// ---- sort pipeline: histogram -> 2-kernel scan -> scatter -----------------
__global__ __launch_bounds__(256) void sort_count(
    const float* __restrict__ x, int* __restrict__ hist)
{
    int p = blockIdx.x * 256 + threadIdx.x;
    if (p >= NPTS) return;
    unsigned b = bucket_of(x[p * 3], x[p * 3 + 1], x[p * 3 + 2]);
    atomicAdd(&hist[b], 1);
}

// K1: per-256-bucket block sums (NBLK blocks)
__global__ __launch_bounds__(256) void scan_partial(
    const int* __restrict__ hist, int* __restrict__ bsum)
{
    __shared__ int s[256];
    int t = threadIdx.x;
    s[t] = hist[blockIdx.x * 256 + t];
    __syncthreads();
    for (int o = 128; o > 0; o >>= 1) {
        if (t < o) s[t] += s[t + o];
        __syncthreads();
    }
    if (t == 0) bsum[blockIdx.x] = s[0];
}

// K2: local scan + in-block reduction of preceding block sums (merged top)
__global__ __launch_bounds__(256) void scan_final(
    const int* __restrict__ hist, const int* __restrict__ bsum,
    int* __restrict__ ofs)
{
    __shared__ int s[256];
    __shared__ int bp;
    int t = threadIdx.x;
    int v = hist[blockIdx.x * 256 + t];
    s[t] = v;
    // wave 0, lanes 0..127: reduce bsum[0..blockIdx-1] via shuffle
    if (t < 64) {
        int acc = 0;
        for (int i = t; i < (int)blockIdx.x; i += 64) acc += bsum[i];
#pragma unroll
        for (int o = 32; o > 0; o >>= 1) acc += __shfl_down(acc, o, 64);
        if (t == 0) bp = acc;
    }
    __syncthreads();
    for (int o = 1; o < 256; o <<= 1) {
        int u = (t >= o) ? s[t - o] : 0;
        __syncthreads();
        s[t] += u;
        __syncthreads();
    }
    ofs[blockIdx.x * 256 + t] = bp + s[t] - v;
}

__global__ __launch_bounds__(256) void sort_scatter(
    const float* __restrict__ x, int* __restrict__ ofs,
    float4* __restrict__ sx, int* __restrict__ perm)
{
    int p = blockIdx.x * 256 + threadIdx.x;
    if (p >= NPTS) return;
    float x0 = x[p * 3], x1 = x[p * 3 + 1], x2 = x[p * 3 + 2];
    unsigned b = bucket_of(x0, x1, x2);
    int pos = atomicAdd(&ofs[b], 1);
    sx[pos] = make_float4(x0, x1, x2, 0.f);
    perm[pos] = p;
}

// ---- gather: per-XCD task stream ------------------------------------------
// blockIdx%8 -> XCD. Each XCD's TASKS units, issued in order:
//   [0, CHUNKS+POOL_A): Bresenham interleave of
//       anchors (level 8+xcd, L2-request-bound) with
//       pool levels 0..5 (L1-resident after Morton sort, VALU-bound)
//     -> coarse-level work executes in the anchor's L2-stall shadow.
//   [CHUNKS+POOL_A, TASKS): trailing pool levels 6,7 (L2-hungry; kept out of
//     the anchor phase so they don't thrash the anchor's 4MB slice).
template <bool SORTED>
__global__ __launch_bounds__(256) void mhe_gather(
    const float* __restrict__ x, const float4* __restrict__ sx,
    const float* __restrict__ tbl, float2* __restrict__ ws, ResArgs ra)
{
    const int AB = CHUNKS + POOL_A;           // 3424
    int b = blockIdx.x;
    int xcd = b & 7;
    int t = b >> 3;                           // 0 .. TASKS-1
    int l, chunk;
    if (t < AB) {
        // Bresenham split: slot t is an anchor iff floor((t+1)*C/AB) advances
        int lo = (int)((long long)t * CHUNKS / AB);
        int hi = (int)((long long)(t + 1) * CHUNKS / AB);
        if (hi > lo) {                        // anchor task
            l = 8 + xcd;
            chunk = lo;
        } else {                              // interleaved pool (levels 0..5)
            int u = t - hi;                   // 0 .. POOL_A-1
            int pl = u / SLICE;
            int sc = u - pl * SLICE;
            l = pl;
            chunk = xcd * SLICE + sc;
            if (chunk >= CHUNKS) return;
        }
    } else {                                  // trailing pool (levels 6,7)
        int u = t - AB;                       // 0 .. POOL_B-1
        int pl = 6 + u / SLICE;
        int sc = u % SLICE;
        l = pl;
        chunk = xcd * SLICE + sc;
        if (chunk >= CHUNKS) return;
    }
    int p = chunk * 256 + threadIdx.x;
    if (p >= NPTS) return;

    float x0, x1, x2;
    if (SORTED) { float4 v = sx[p]; x0 = v.x; x1 = v.y; x2 = v.z; }
    else        { x0 = x[p * 3]; x1 = x[p * 3 + 1]; x2 = x[p * 3 + 2]; }

    float2 o = mhe_core(x0, x1, x2, tbl, l, ra.r[l]);
    ws[(size_t)l * NPTS + p] = o;   // coalesced (p = sorted position)
}

// ---- transpose + un-permute: ws[l][sp] -> out[perm[sp]][l] ---------------
// Each output point is one FULL 128B region (16 x float2), so scattered
// per-point writes cost the same line count as coalesced.
template <bool PERM>
__global__ __launch_bounds__(256) void mhe_transpose(
    const float2* __restrict__ ws, const int* __restrict__ perm,
    float2* __restrict__ out)
{
    __shared__ float2 tile[16][65];
    __shared__ int pidx[64];
    int p0 = blockIdx.x * 64;
    int t = threadIdx.x;

    int pc = t & 63;
#pragma unroll
    for (int i = 0; i < 4; ++i) {
        int l = (t >> 6) + i * 4;
        int p = p0 + pc;
        if (p < NPTS) tile[l][pc] = ws[(size_t)l * NPTS + p];
    }
    if (PERM && t < 64) {
        int p = p0 + t;
        pidx[t] = (p < NPTS) ? perm[p] : 0;
    }
    __syncthreads();

    float4* out4 = (float4*)out;
#pragma unroll
    for (int i = 0; i < 2; ++i) {
        int idx = t + i * 256;      // 512 float4 per block
        int pt = idx >> 3, q = idx & 7;
        int p = p0 + pt;
        if (p >= NPTS) continue;
        int dp = PERM ? pidx[pt] : p;
        float2 a = tile[2 * q][pt];
        float2 b2 = tile[2 * q + 1][pt];
        out4[(size_t)dp * 8 + q] = make_float4(a.x, a.y, b2.x, b2.y);
    }
}

// ---- Fallback: direct-out single kernel (tiny ws) ------------------------
__global__ __launch_bounds__(256) void mhe_direct(
    const float* __restrict__ x, const float* __restrict__ tbl,
    float* __restrict__ out, ResArgs ra)
{
    int gid = blockIdx.x * 256 + threadIdx.x;
    int p = gid >> 4;
    int l = gid & 15;
    if (p >= NPTS) return;
    float2 o = mhe_core(x[p * 3], x[p * 3 + 1], x[p * 3 + 2], tbl, l, ra.r[l]);
    ((float2*)out)[(size_t)p * 16 + l] = o;
}

extern "C" void kernel_launch(void* const* d_in, const int* in_sizes, int n_in,
                              void* d_out, int out_size, void* d_ws, size_t ws_size,
                              hipStream_t stream) {
    const float* x   = (const float*)d_in[0];
    const float* tbl = (const float*)d_in[1];
    float* out = (float*)d_out;

    // RES computed on HOST with libm doubles (bit-exact vs numpy): levels
    // 3,6,9,12,15 land exactly on 32/64/128/256/512; device ulp flips floor().
    ResArgs ra;
    double bb = exp((log(512.0) - log(16.0)) / 15.0);
    for (int l = 0; l < 16; ++l)
        ra.r[l] = (float)floor(16.0 * pow(bb, (double)l));

    // ws carve-up (bytes)
    const size_t WS_LV   = 0;                       // float2[16][NPTS] = 64 MB
    const size_t WS_SX   = 64000000;                // float4[NPTS]    =  8 MB
    const size_t WS_PERM = 72000000;                // int[NPTS]       =  2 MB
    const size_t WS_HIST = 74000000;                // int[NBKT]
    const size_t WS_OFS  = 74131072;                // int[NBKT]
    const size_t WS_BSUM = 74262144;                // int[NBLK]
    const size_t WS_NEW  = 74263168;
    const size_t WS_T2   = (size_t)NPTS * 16 * sizeof(float2);  // 64 MB

    int gather_grid = 8 * TASKS;                    // 31312
    int tp_grid = (NPTS + 63) / 64;                 // 7813

    if (ws_size >= WS_NEW) {
        char* w = (char*)d_ws;
        float2* ws_lv = (float2*)(w + WS_LV);
        float4* sx    = (float4*)(w + WS_SX);
        int* perm     = (int*)(w + WS_PERM);
        int* hist     = (int*)(w + WS_HIST);
        int* ofs      = (int*)(w + WS_OFS);
        int* bsum     = (int*)(w + WS_BSUM);

        hipMemsetAsync(hist, 0, NBKT * sizeof(int), stream);
        sort_count<<<CHUNKS, 256, 0, stream>>>(x, hist);
        scan_partial<<<NBLK, 256, 0, stream>>>(hist, bsum);
        scan_final<<<NBLK, 256, 0, stream>>>(hist, bsum, ofs);
        sort_scatter<<<CHUNKS, 256, 0, stream>>>(x, ofs, sx, perm);

        mhe_gather<true><<<gather_grid, 256, 0, stream>>>(x, sx, tbl, ws_lv, ra);
        mhe_transpose<true><<<tp_grid, 256, 0, stream>>>(ws_lv, perm,
                                                         (float2*)out);
    } else if (ws_size >= WS_T2) {
        float2* ws_lv = (float2*)d_ws;
        mhe_gather<false><<<gather_grid, 256, 0, stream>>>(x, nullptr, tbl,
                                                           ws_lv, ra);
        mhe_transpose<false><<<tp_grid, 256, 0, stream>>>(ws_lv, nullptr,
                                                          (float2*)out);
    } else {
        mhe_direct<<<(NPTS * 16 + 255) / 256, 256, 0, stream>>>(x, tbl, out, ra);
    }
}